// Round 1
// 365.742 us; speedup vs baseline: 1.0780x; 1.0780x over previous
//
#include <hip/hip_runtime.h>
#include <hip/hip_bf16.h>

typedef unsigned long long u64;
typedef float f32x4 __attribute__((ext_vector_type(4)));

#define H_SZ 4096
#define NBITS 16
#define NFEAT 128
#define NCLS 10
#define THETA 8

// Bit-packing convention (weights and acts must match; popcount is order-
// agnostic given agreement): for a chunk c of 256 positions, word (c,j),
// j=0..3, has bit i <-> position p = c*256 + 4*i + j. This is exactly what
// per-component ballots of a lane-major float4 load produce.

// ---------------------------------------------------------------------------
// Encode: x[64,128] -> thermometer bits packed per convention.
// actp0[(c*4+j)*64 + b], c=0..7 (P0=2048, 32 words).
// Thread (c,j,b): needs features f = c*16..c*16+15; bit i=4k+m set iff
// x[b][c*16+k] >= thr(t) with t = 4m+j. 16 loads/thread, 4 thresholds.
// ---------------------------------------------------------------------------
__global__ void encode_kernel(const float* __restrict__ x, u64* __restrict__ actp0) {
    int idx = blockIdx.x * blockDim.x + threadIdx.x;   // 0..2047
    if (idx >= 32 * 64) return;
    int wword = idx >> 6;        // 0..31
    int b = idx & 63;
    int c = wword >> 2, j = wword & 3;
    // identical fp32 math to ref: thr = (t+1)/(NBITS+1), t = 4m+j
    float thr0 = (4 * 0 + j + 1.0f) / (NBITS + 1.0f);
    float thr1 = (4 * 1 + j + 1.0f) / (NBITS + 1.0f);
    float thr2 = (4 * 2 + j + 1.0f) / (NBITS + 1.0f);
    float thr3 = (4 * 3 + j + 1.0f) / (NBITS + 1.0f);
    const float* xb = x + b * NFEAT + c * 16;
    u64 word = 0;
    #pragma unroll
    for (int k = 0; k < 16; k++) {
        float xv = xb[k];
        word |= (u64)(xv >= thr0) << (4 * k + 0);
        word |= (u64)(xv >= thr1) << (4 * k + 1);
        word |= (u64)(xv >= thr2) << (4 * k + 2);
        word |= (u64)(xv >= thr3) << (4 * k + 3);
    }
    actp0[wword * 64 + b] = word;
}

// ---------------------------------------------------------------------------
// Layer: wave = 2 (h,s) rows, interleaved in one chunk loop.
//  - two independent nontemporal float4 load streams (one per row)
//  - act words read from LDS once per chunk, shared by both rows
//  - partial unroll (4) + launch_bounds(256,4): VGPR <= 128, 16 waves/CU
// grid: 1024 blocks x 256 thr = 4096 waves x 2 rows = 8192 (h,s) rows.
// ---------------------------------------------------------------------------
template <int P>
__global__ __launch_bounds__(256, 4) void layer_kernel(const float* __restrict__ W,
                                                       const u64* __restrict__ actp,
                                                       u64* __restrict__ ballots) {
    constexpr int NW = P / 64;               // act words
    __shared__ __align__(16) u64 lds[NW * 64];   // 16 KB (P=2048) / 32 KB (P=4096)
    int tid = threadIdx.x;
    // vectorized staging: 16 B per thread per step
    const ulonglong2* src = (const ulonglong2*)actp;
    ulonglong2* dst = (ulonglong2*)lds;
    #pragma unroll
    for (int i = tid; i < NW * 32; i += 256) dst[i] = src[i];
    __syncthreads();

    int lane = tid & 63;
    int warp = tid >> 6;
    int wid0 = (blockIdx.x * 4 + warp) * 2;             // first (h,s) id
    const f32x4* w0 = (const f32x4*)(W + (size_t)wid0 * P) + lane;
    const f32x4* w1 = (const f32x4*)(W + (size_t)(wid0 + 1) * P) + lane;

    unsigned int zp0 = 0, zn0 = 0, zp1 = 0, zn1 = 0;
    #pragma unroll 4
    for (int c = 0; c < P / 256; c++) {
        f32x4 a = __builtin_nontemporal_load(w0 + c * 64);
        f32x4 b = __builtin_nontemporal_load(w1 + c * 64);
        u64 A0 = lds[(c * 4 + 0) * 64 + lane];
        u64 A1 = lds[(c * 4 + 1) * 64 + lane];
        u64 A2 = lds[(c * 4 + 2) * 64 + lane];
        u64 A3 = lds[(c * 4 + 3) * 64 + lane];

        u64 m;
        m = __ballot(a.x > 0.0f); zp0 += __builtin_popcountll(A0 & m);
        m = __ballot(a.x < 0.0f); zn0 += __builtin_popcountll(A0 & m);
        m = __ballot(a.y > 0.0f); zp0 += __builtin_popcountll(A1 & m);
        m = __ballot(a.y < 0.0f); zn0 += __builtin_popcountll(A1 & m);
        m = __ballot(a.z > 0.0f); zp0 += __builtin_popcountll(A2 & m);
        m = __ballot(a.z < 0.0f); zn0 += __builtin_popcountll(A2 & m);
        m = __ballot(a.w > 0.0f); zp0 += __builtin_popcountll(A3 & m);
        m = __ballot(a.w < 0.0f); zn0 += __builtin_popcountll(A3 & m);

        m = __ballot(b.x > 0.0f); zp1 += __builtin_popcountll(A0 & m);
        m = __ballot(b.x < 0.0f); zn1 += __builtin_popcountll(A0 & m);
        m = __ballot(b.y > 0.0f); zp1 += __builtin_popcountll(A1 & m);
        m = __ballot(b.y < 0.0f); zn1 += __builtin_popcountll(A1 & m);
        m = __ballot(b.z > 0.0f); zp1 += __builtin_popcountll(A2 & m);
        m = __ballot(b.z < 0.0f); zn1 += __builtin_popcountll(A2 & m);
        m = __ballot(b.w > 0.0f); zp1 += __builtin_popcountll(A3 & m);
        m = __ballot(b.w < 0.0f); zn1 += __builtin_popcountll(A3 & m);
    }
    int z0 = (int)zp0 - (int)zn0;
    int z1 = (int)zp1 - (int)zn1;
    u64 f0 = __ballot(z0 >= THETA);
    u64 f1 = __ballot(z1 >= THETA);
    if (lane == 0) {
        ballots[wid0] = f0;
        ballots[wid0 + 1] = f1;
    }
}

// ---------------------------------------------------------------------------
// Transpose: ballots[h*2+s] (bit b = batch) -> f[h] = OR of segs (batch-major,
// for output kernel) + next-layer act words in the interleaved convention.
// grid: 16 blocks (one per chunk c of 256 h) x 256 threads (j*64+b).
// ---------------------------------------------------------------------------
__global__ void transpose_kernel(const u64* __restrict__ ballots,
                                 u64* __restrict__ f,
                                 u64* __restrict__ actp) {
    __shared__ u64 lds[256];
    int c = blockIdx.x;
    int tid = threadIdx.x;
    int h = c * 256 + tid;
    u64 fh = ballots[2 * h] | ballots[2 * h + 1];
    f[h] = fh;
    lds[tid] = fh;
    __syncthreads();
    int j = tid >> 6, b = tid & 63;
    u64 word = 0;
    #pragma unroll 8
    for (int i = 0; i < 64; i++)
        word |= ((lds[4 * i + j] >> b) & 1ULL) << i;
    actp[(c * 4 + j) * 64 + b] = word;
}

// ---------------------------------------------------------------------------
// Output: out[b,c] = sum_l sum_h fired_l[b,h] * outW[l,h,c]. lane = batch.
// l==2 reads the (still-live) layer-2 ballots directly and ORs the two
// segments inline — the third transpose kernel is gone.
// grid: 480 blocks x 256 thr = 1920 waves (3 x 10 x 64 chunks of 64 h).
// ---------------------------------------------------------------------------
__global__ void output_kernel(const float* __restrict__ outW,
                              const u64* __restrict__ f,
                              const u64* __restrict__ ballots,
                              float* __restrict__ out) {
    int tid = threadIdx.x;
    int lane = tid & 63;
    int wid = blockIdx.x * 4 + (tid >> 6);   // 0..1919
    int l = wid / (NCLS * 64);
    int rem = wid % (NCLS * 64);
    int c = rem / 64;
    int chunk = rem % 64;
    int h0 = chunk * 64;
    float acc = 0.0f;
    if (l < 2) {
        const u64* fl = f + l * H_SZ;
        #pragma unroll 8
        for (int h = h0; h < h0 + 64; h++) {
            float wv = outW[((size_t)(l * H_SZ + h)) * NCLS + c];
            if ((fl[h] >> lane) & 1ULL) acc += wv;
        }
    } else {
        #pragma unroll 8
        for (int h = h0; h < h0 + 64; h++) {
            float wv = outW[((size_t)(2 * H_SZ + h)) * NCLS + c];
            u64 ball = ballots[2 * h] | ballots[2 * h + 1];
            if ((ball >> lane) & 1ULL) acc += wv;
        }
    }
    atomicAdd(&out[lane * NCLS + c], acc);
}

// ---------------------------------------------------------------------------
extern "C" void kernel_launch(void* const* d_in, const int* in_sizes, int n_in,
                              void* d_out, int out_size, void* d_ws, size_t ws_size,
                              hipStream_t stream) {
    const float* x    = (const float*)d_in[0];
    const float* W0   = (const float*)d_in[1];
    const float* W1   = (const float*)d_in[2];
    const float* W2   = (const float*)d_in[3];
    const float* outW = (const float*)d_in[4];
    float* out = (float*)d_out;

    // workspace layout (16B-aligned)
    char* ws = (char*)d_ws;
    u64* actp0   = (u64*)(ws);                    // 2048 u64  = 16 KB
    u64* actp1   = (u64*)(ws + 16384);            // 4096 u64  = 32 KB
    u64* actp2   = (u64*)(ws + 49152);            // 4096 u64  = 32 KB
    u64* ballots = (u64*)(ws + 81920);            // 8192 u64  = 64 KB
    u64* f       = (u64*)(ws + 147456);           // 2*4096 u64 = 64 KB

    hipMemsetAsync(d_out, 0, (size_t)out_size * sizeof(float), stream);

    encode_kernel<<<8, 256, 0, stream>>>(x, actp0);

    layer_kernel<2048><<<1024, 256, 0, stream>>>(W0, actp0, ballots);
    transpose_kernel<<<16, 256, 0, stream>>>(ballots, f + 0 * H_SZ, actp1);

    layer_kernel<4096><<<1024, 256, 0, stream>>>(W1, actp1, ballots);
    transpose_kernel<<<16, 256, 0, stream>>>(ballots, f + 1 * H_SZ, actp2);

    layer_kernel<4096><<<1024, 256, 0, stream>>>(W2, actp2, ballots);

    output_kernel<<<480, 256, 0, stream>>>(outW, f, ballots, out);
}

// Round 2
// 342.846 us; speedup vs baseline: 1.1499x; 1.0668x over previous
//
#include <hip/hip_runtime.h>
#include <hip/hip_bf16.h>

typedef unsigned long long u64;
typedef float f32x4 __attribute__((ext_vector_type(4)));

#define H_SZ 4096
#define NBITS 16
#define NFEAT 128
#define NCLS 10
#define THETA 8

// Bit-packing convention: for a chunk c of 256 positions, act word (c,j),
// j=0..3, has bit i <-> position p = c*256 + 4*i + j. This is exactly what
// per-component ballots of a lane-major float4 load produce.

// ---------------------------------------------------------------------------
// Encode: x[64,128] -> thermometer bits packed per convention.
// actp0[(c*4+j)*64 + b], c=0..7 (P0=2048, 32 words).
// ---------------------------------------------------------------------------
__global__ void encode_kernel(const float* __restrict__ x, u64* __restrict__ actp0) {
    int idx = blockIdx.x * blockDim.x + threadIdx.x;   // 0..2047
    if (idx >= 32 * 64) return;
    int wword = idx >> 6;        // 0..31
    int b = idx & 63;
    int c = wword >> 2, j = wword & 3;
    // identical fp32 math to ref: thr = (t+1)/(NBITS+1), t = 4m+j
    float thr0 = (4 * 0 + j + 1.0f) / (NBITS + 1.0f);
    float thr1 = (4 * 1 + j + 1.0f) / (NBITS + 1.0f);
    float thr2 = (4 * 2 + j + 1.0f) / (NBITS + 1.0f);
    float thr3 = (4 * 3 + j + 1.0f) / (NBITS + 1.0f);
    const float* xb = x + b * NFEAT + c * 16;
    u64 word = 0;
    #pragma unroll
    for (int k = 0; k < 16; k++) {
        float xv = xb[k];
        word |= (u64)(xv >= thr0) << (4 * k + 0);
        word |= (u64)(xv >= thr1) << (4 * k + 1);
        word |= (u64)(xv >= thr2) << (4 * k + 2);
        word |= (u64)(xv >= thr3) << (4 * k + 3);
    }
    actp0[wword * 64 + b] = word;
}

// ---------------------------------------------------------------------------
// 64x64 bit-matrix transpose, rows distributed across the 64 lanes.
// In: lane l holds row l (bit b = M[l][b]). Out: lane l holds column l
// (bit i = M[i][l]). 6 butterfly stages; block-swap recursion:
//   new(r,c) = old(r^d, c^d) when (r&d) != (c&d)
// ---------------------------------------------------------------------------
__device__ __forceinline__ u64 bfly_stage(u64 x, int lane, int d, u64 Md) {
    u64 p = __shfl_xor(x, d);
    return (lane & d) ? ((x & Md) | ((p >> d) & ~Md))
                      : ((x & ~Md) | ((p << d) & Md));
}

__device__ __forceinline__ u64 transpose64(u64 x, int lane) {
    x = bfly_stage(x, lane, 32, 0xFFFFFFFF00000000ULL);
    x = bfly_stage(x, lane, 16, 0xFFFF0000FFFF0000ULL);
    x = bfly_stage(x, lane,  8, 0xFF00FF00FF00FF00ULL);
    x = bfly_stage(x, lane,  4, 0xF0F0F0F0F0F0F0F0ULL);
    x = bfly_stage(x, lane,  2, 0xCCCCCCCCCCCCCCCCULL);
    x = bfly_stage(x, lane,  1, 0xAAAAAAAAAAAAAAAAULL);
    return x;
}

// ---------------------------------------------------------------------------
// Layer: wave = neuron h, both segments (rows 2h, 2h+1), interleaved in one
// chunk loop. Emits fired[h] (bit=batch) directly — no ballots array, no
// separate transpose kernel.
//  - FROM_FIRED: act staging = in-block 64x64 butterfly transpose of the
//    previous layer's fired[] (group (c,j): IN[i] = fired[c*256+4i+j]).
//  - first 4 chunks' nontemporal loads are peeled ABOVE staging so HBM
//    streams while the butterfly/copy runs.
// grid: 1024 blocks x 256 thr = 4096 waves = 4096 h.
// ---------------------------------------------------------------------------
template <int P, bool FROM_FIRED>
__global__ __launch_bounds__(256, 4) void layer_kernel(const float* __restrict__ W,
                                                       const u64* __restrict__ actin,
                                                       u64* __restrict__ fired_out) {
    constexpr int NW = P / 64;               // act words
    constexpr int NC = P / 256;              // chunks
    __shared__ __align__(16) u64 lds[NW * 64];   // 16 KB (P=2048) / 32 KB (P=4096)
    int tid = threadIdx.x;
    int lane = tid & 63;
    int warp = tid >> 6;
    int h = blockIdx.x * 4 + warp;           // 0..4095
    const f32x4* w0 = (const f32x4*)(W + (size_t)(2 * h) * P) + lane;
    const f32x4* w1 = (const f32x4*)(W + (size_t)(2 * h + 1) * P) + lane;

    // peel: first 4 chunks (8 x 1KB/wave) in flight during staging
    f32x4 pa[4], pb[4];
    #pragma unroll
    for (int c = 0; c < 4; c++) {
        pa[c] = __builtin_nontemporal_load(w0 + c * 64);
        pb[c] = __builtin_nontemporal_load(w1 + c * 64);
    }

    if constexpr (FROM_FIRED) {
        // warp w builds j=w words for all c: IN[lane] = fired[c*256+4*lane+w]
        #pragma unroll 4
        for (int c = 0; c < 16; c++) {
            u64 xw = actin[c * 256 + 4 * lane + warp];
            xw = transpose64(xw, lane);
            lds[(c * 4 + warp) * 64 + lane] = xw;
        }
    } else {
        const ulonglong2* src = (const ulonglong2*)actin;
        ulonglong2* dst = (ulonglong2*)lds;
        #pragma unroll
        for (int i = tid; i < NW * 32; i += 256) dst[i] = src[i];
    }
    __syncthreads();

    unsigned int zp0 = 0, zn0 = 0, zp1 = 0, zn1 = 0;
    auto body = [&](int c, f32x4 a, f32x4 b) {
        u64 A0 = lds[(c * 4 + 0) * 64 + lane];
        u64 A1 = lds[(c * 4 + 1) * 64 + lane];
        u64 A2 = lds[(c * 4 + 2) * 64 + lane];
        u64 A3 = lds[(c * 4 + 3) * 64 + lane];
        u64 m;
        m = __ballot(a.x > 0.0f); zp0 += __builtin_popcountll(A0 & m);
        m = __ballot(a.x < 0.0f); zn0 += __builtin_popcountll(A0 & m);
        m = __ballot(a.y > 0.0f); zp0 += __builtin_popcountll(A1 & m);
        m = __ballot(a.y < 0.0f); zn0 += __builtin_popcountll(A1 & m);
        m = __ballot(a.z > 0.0f); zp0 += __builtin_popcountll(A2 & m);
        m = __ballot(a.z < 0.0f); zn0 += __builtin_popcountll(A2 & m);
        m = __ballot(a.w > 0.0f); zp0 += __builtin_popcountll(A3 & m);
        m = __ballot(a.w < 0.0f); zn0 += __builtin_popcountll(A3 & m);

        m = __ballot(b.x > 0.0f); zp1 += __builtin_popcountll(A0 & m);
        m = __ballot(b.x < 0.0f); zn1 += __builtin_popcountll(A0 & m);
        m = __ballot(b.y > 0.0f); zp1 += __builtin_popcountll(A1 & m);
        m = __ballot(b.y < 0.0f); zn1 += __builtin_popcountll(A1 & m);
        m = __ballot(b.z > 0.0f); zp1 += __builtin_popcountll(A2 & m);
        m = __ballot(b.z < 0.0f); zn1 += __builtin_popcountll(A2 & m);
        m = __ballot(b.w > 0.0f); zp1 += __builtin_popcountll(A3 & m);
        m = __ballot(b.w < 0.0f); zn1 += __builtin_popcountll(A3 & m);
    };

    #pragma unroll
    for (int c = 0; c < 4; c++) body(c, pa[c], pb[c]);
    #pragma unroll 4
    for (int c = 4; c < NC; c++) {
        f32x4 a = __builtin_nontemporal_load(w0 + c * 64);
        f32x4 b = __builtin_nontemporal_load(w1 + c * 64);
        body(c, a, b);
    }

    int z0 = (int)zp0 - (int)zn0;
    int z1 = (int)zp1 - (int)zn1;
    u64 f0 = __ballot(z0 >= THETA);
    u64 f1 = __ballot(z1 >= THETA);
    if (lane == 0) fired_out[h] = f0 | f1;
}

// ---------------------------------------------------------------------------
// Output: out[b,c] = sum_l sum_h fired_l[b,h] * outW[l,h,c]. lane = batch.
// Reads fired[] directly (no f/ballots arrays). Block-uniform (l,c)
// (64-wid groups are 4-aligned), so 4 wave-partials reduce in LDS ->
// one atomicAdd per (block, lane): 48 adds/element instead of 192.
// grid: 480 blocks x 256 thr = 1920 waves (3 x 10 x 64 chunks of 64 h).
// ---------------------------------------------------------------------------
__global__ void output_kernel(const float* __restrict__ outW,
                              const u64* __restrict__ fired,
                              float* __restrict__ out) {
    __shared__ float red[4][64];
    int tid = threadIdx.x;
    int lane = tid & 63;
    int warp = tid >> 6;
    int wid = blockIdx.x * 4 + warp;   // 0..1919
    int l = wid / (NCLS * 64);
    int rem = wid % (NCLS * 64);
    int c = rem / 64;
    int chunk = rem % 64;
    const u64* fl = fired + l * H_SZ;
    int h0 = chunk * 64;
    float acc = 0.0f;
    #pragma unroll 8
    for (int h = h0; h < h0 + 64; h++) {
        float wv = outW[((size_t)(l * H_SZ + h)) * NCLS + c];
        if ((fl[h] >> lane) & 1ULL) acc += wv;
    }
    red[warp][lane] = acc;
    __syncthreads();
    if (warp == 0) {
        float s = red[0][lane] + red[1][lane] + red[2][lane] + red[3][lane];
        atomicAdd(&out[lane * NCLS + c], s);
    }
}

// ---------------------------------------------------------------------------
extern "C" void kernel_launch(void* const* d_in, const int* in_sizes, int n_in,
                              void* d_out, int out_size, void* d_ws, size_t ws_size,
                              hipStream_t stream) {
    const float* x    = (const float*)d_in[0];
    const float* W0   = (const float*)d_in[1];
    const float* W1   = (const float*)d_in[2];
    const float* W2   = (const float*)d_in[3];
    const float* outW = (const float*)d_in[4];
    float* out = (float*)d_out;

    // workspace layout (16B-aligned)
    char* ws = (char*)d_ws;
    u64* actp0 = (u64*)(ws);             // 2048 u64 = 16 KB
    u64* fired = (u64*)(ws + 16384);     // 3*4096 u64 = 96 KB (bit b = batch)

    hipMemsetAsync(d_out, 0, (size_t)out_size * sizeof(float), stream);

    encode_kernel<<<8, 256, 0, stream>>>(x, actp0);

    layer_kernel<2048, false><<<1024, 256, 0, stream>>>(W0, actp0, fired + 0 * H_SZ);
    layer_kernel<4096, true ><<<1024, 256, 0, stream>>>(W1, fired + 0 * H_SZ, fired + 1 * H_SZ);
    layer_kernel<4096, true ><<<1024, 256, 0, stream>>>(W2, fired + 1 * H_SZ, fired + 2 * H_SZ);

    output_kernel<<<480, 256, 0, stream>>>(outW, fired, out);
}